// Round 14
// baseline (4578.194 us; speedup 1.0000x reference)
//
#include <hip/hip_runtime.h>

#define NB 8
#define NPTS 16384
#define NPOINT 512
#define NSAMPLE 64
#define CIN 64
#define PARTS 4
#define PPB (NPTS / PARTS)     // 4096 points per block

typedef float v2f __attribute__((ext_vector_type(2)));
typedef unsigned long long u64;

template <int CTRL>
__device__ __forceinline__ float dpp_f(float x) {
    int xi = __builtin_bit_cast(int, x);
    int yi = __builtin_amdgcn_update_dpp(xi, xi, CTRL, 0xF, 0xF, false);
    return __builtin_bit_cast(float, yi);
}
template <int CTRL>
__device__ __forceinline__ int dpp_i(int x) {
    return __builtin_amdgcn_update_dpp(x, x, CTRL, 0xF, 0xF, false);
}

// wave64 max reduce -> true result in lane 63
__device__ __forceinline__ float wave_max_f(float x) {
    x = fmaxf(x, dpp_f<0x111>(x));
    x = fmaxf(x, dpp_f<0x112>(x));
    x = fmaxf(x, dpp_f<0x114>(x));
    x = fmaxf(x, dpp_f<0x118>(x));
    x = fmaxf(x, dpp_f<0x142>(x));
    x = fmaxf(x, dpp_f<0x143>(x));
    return x;
}
__device__ __forceinline__ int wave_min_i(int x) {
    x = min(x, dpp_i<0x111>(x));
    x = min(x, dpp_i<0x112>(x));
    x = min(x, dpp_i<0x114>(x));
    x = min(x, dpp_i<0x118>(x));
    x = min(x, dpp_i<0x142>(x));
    x = min(x, dpp_i<0x143>(x));
    return x;
}

#define CMB(va, ia, vb, ib) { bool t_ = ((vb) > (va)) || (((vb) == (va)) && ((ib) < (ia))); \
                              if (t_) { (va) = (vb); (ia) = (ib); } }

// ---------------- feature transpose (B,C,N) -> (B,N,C) ----------------
__global__ __launch_bounds__(256) void transpose_kernel(
    const float* __restrict__ feats, float* __restrict__ feats_t)
{
    __shared__ float t[64][65];
    int blk = blockIdx.x;                       // 0..2047
    int b = blk & 7, tile = blk >> 3, n0 = tile * 64;
    int cc = threadIdx.x & 63, rr = threadIdx.x >> 6;   // rr 0..3
    const float* fb = feats + (size_t)b * CIN * NPTS;
    #pragma unroll
    for (int k = 0; k < 16; ++k) {
        int c = k * 4 + rr;
        t[c][cc] = fb[(size_t)c * NPTS + n0 + cc];
    }
    __syncthreads();
    float* fo = feats_t + ((size_t)b * NPTS + n0) * CIN;
    #pragma unroll
    for (int k = 0; k < 16; ++k) {
        int n = k * 4 + rr;
        fo[(size_t)n * CIN + cc] = t[cc][n];
    }
}

// ---------------- FPS: 4 blocks per batch, device-scope u64 message passing ----------------
// slot u64 = (valbits << 32) | (j << 14) | idx   (idx < 16384, j < 512 -> lo32 < 2^23)
// Stale-tolerant: FPS is deterministic, so a stale tag-matching value equals the fresh one.
__global__ __launch_bounds__(512) void fps_kernel(
    const float* __restrict__ xyz, int* __restrict__ fps_idx, u64* __restrict__ slots)
{
    __shared__ __align__(16) int s_pair[2][8][2];

    const int blk = blockIdx.x;                 // 0..31
    const int b = blk >> 2, part = blk & 3;
    const int tid = threadIdx.x;
    const int wv = tid >> 6, ln = tid & 63;
    const float* xb = xyz + (size_t)b * NPTS * 3;
    const int base = part * PPB + tid * 8;      // first point (index within batch)

    // load 8 contiguous points, deinterleaved into packed pairs (24 + 8 regs)
    v2f px2[4], py2[4], pz2[4], dd2[4];
    {
        const float4* xb4 = (const float4*)(xb + (size_t)base * 3);
        #pragma unroll
        for (int q = 0; q < 2; ++q) {           // 4 points per group (3 float4)
            float4 f0 = xb4[3 * q + 0];
            float4 f1 = xb4[3 * q + 1];
            float4 f2 = xb4[3 * q + 2];
            px2[2 * q + 0] = (v2f){f0.x, f0.w};
            py2[2 * q + 0] = (v2f){f0.y, f1.x};
            pz2[2 * q + 0] = (v2f){f0.z, f1.y};
            px2[2 * q + 1] = (v2f){f1.z, f2.y};
            py2[2 * q + 1] = (v2f){f1.w, f2.z};
            pz2[2 * q + 1] = (v2f){f2.x, f2.w};
        }
        #pragma unroll
        for (int k = 0; k < 4; ++k) dd2[k] = (v2f){1e10f, 1e10f};
    }
    if (tid == 0 && part == 0) fps_idx[b * NPOINT] = 0;
    float cx = xb[0], cy = xb[1], cz = xb[2];   // centroid 0 = point 0
    u64* myslots = slots + b * 8;               // [parity][part]

    for (int j = 1; j < NPOINT; ++j) {
        #pragma clang fp contract(off)
        const int p = j & 1;
        v2f ncx = (v2f){-cx, -cx};
        v2f ncy = (v2f){-cy, -cy};
        v2f ncz = (v2f){-cz, -cz};
        // ---- packed distance update + per-thread max (exact numpy rounding) ----
        float bm = -1.0f;
        #pragma unroll
        for (int k = 0; k < 4; ++k) {
            v2f dx = px2[k] + ncx;              // a + (-c) == a - c exactly
            v2f dy = py2[k] + ncy;
            v2f dz = pz2[k] + ncz;
            v2f s1 = dx * dx + dy * dy;         // contract off: each op rounded
            v2f d2 = s1 + dz * dz;              // (dx²+dy²)+dz² — numpy association
            v2f nd = __builtin_elementwise_min(dd2[k], d2);
            dd2[k] = nd;
            bm = fmaxf(bm, fmaxf(nd.x, nd.y));
        }
        // ---- wave max via DPP ----
        float wm = wave_max_f(bm);
        float wmax = __builtin_bit_cast(float,
            __builtin_amdgcn_readlane(__builtin_bit_cast(int, wm), 63));
        // ---- per-thread first matching sub-index ----
        int mk = 8;
        #pragma unroll
        for (int k = 3; k >= 0; --k) {
            mk = (dd2[k].y == wmax) ? (2 * k + 1) : mk;
            mk = (dd2[k].x == wmax) ? (2 * k)     : mk;
        }
        int mi = (mk == 8) ? 0x7fffffff : (base + mk);
        // ---- wave min-index via DPP; lane 0 publishes to LDS ----
        int rm = wave_min_i(mi);
        int wave_mi = __builtin_amdgcn_readlane(rm, 63);
        if (ln == 0) {
            s_pair[p][wv][0] = __builtin_bit_cast(int, wmax);
            s_pair[p][wv][1] = wave_mi;
        }
        __syncthreads();                        // single barrier per iteration
        // ---- cross-wave argmax over 8 slots (redundant on all threads) ----
        int4 q0 = *(const int4*)&s_pair[p][0][0];
        int4 q1 = *(const int4*)&s_pair[p][2][0];
        int4 q2 = *(const int4*)&s_pair[p][4][0];
        int4 q3 = *(const int4*)&s_pair[p][6][0];
        float v0 = __builtin_bit_cast(float, q0.x); int i0 = q0.y;
        float v1 = __builtin_bit_cast(float, q0.z); int i1 = q0.w;
        float v2 = __builtin_bit_cast(float, q1.x); int i2 = q1.y;
        float v3 = __builtin_bit_cast(float, q1.z); int i3 = q1.w;
        float v4 = __builtin_bit_cast(float, q2.x); int i4 = q2.y;
        float v5 = __builtin_bit_cast(float, q2.z); int i5 = q2.w;
        float v6 = __builtin_bit_cast(float, q3.x); int i6 = q3.y;
        float v7 = __builtin_bit_cast(float, q3.z); int i7 = q3.w;
        CMB(v0, i0, v1, i1); CMB(v2, i2, v3, i3);
        CMB(v4, i4, v5, i5); CMB(v6, i6, v7, i7);
        CMB(v0, i0, v2, i2); CMB(v4, i4, v6, i6);
        CMB(v0, i0, v4, i4);
        // ---- publish block partial: one u64 release-store (tag+payload atomic) ----
        if (tid == 0) {
            u64 msg = ((u64)(unsigned)__builtin_bit_cast(int, v0) << 32)
                    | ((u64)(unsigned)j << 14) | (u64)(unsigned)i0;
            __hip_atomic_store(&myslots[p * PARTS + part], msg,
                               __ATOMIC_RELEASE, __HIP_MEMORY_SCOPE_AGENT);
        }
        // ---- poll all 4 sibling partials for this iteration ----
        float bv = -1.0f; int bi = 0x7fffffff;
        #pragma unroll
        for (int q = 0; q < PARTS; ++q) {
            u64 t;
            do {
                t = __hip_atomic_load(&myslots[p * PARTS + q],
                                      __ATOMIC_ACQUIRE, __HIP_MEMORY_SCOPE_AGENT);
            } while ((unsigned)((t & 0xFFFFFFFFu) >> 14) != (unsigned)j);
            float qv = __builtin_bit_cast(float, (int)(unsigned)(t >> 32));
            int   qi = (int)(t & 0x3FFFu);
            CMB(bv, bi, qv, qi);
        }
        int ch = __builtin_amdgcn_readfirstlane(bi);
        const float* cp = xb + 3 * ch;          // uniform -> scalar loads
        cx = cp[0]; cy = cp[1]; cz = cp[2];
        if (tid == 0 && part == 0) fps_idx[b * NPOINT + j] = ch;
    }
}

// ---------------- fused ball query + gather + MLP(67->64->64->128) + maxpool ----------------
// one wave per centroid
__global__ __launch_bounds__(64) void ballmlp_kernel(
    const float* __restrict__ xyz, const float* __restrict__ feats_t,
    const int* __restrict__ fps_idx,
    const float* __restrict__ W1, const float* __restrict__ b1,
    const float* __restrict__ W2, const float* __restrict__ b2,
    const float* __restrict__ W3, const float* __restrict__ b3,
    float* __restrict__ out)
{
    const float R2 = (float)(0.1 * 0.1);   // double product rounded to f32 (matches numpy)
    int blk = blockIdx.x;
    int b = blk & 7, j = blk >> 3;
    int s = threadIdx.x;
    int cent = b * NPOINT + j;
    const float* xb = xyz + (size_t)b * NPTS * 3;

    __shared__ float X[67][64];   // column-major: X[c][s] -> lane-contiguous, conflict-free
    __shared__ int slots[64];

    int cidx = fps_idx[cent];
    float cx = xb[3 * cidx + 0];
    float cy = xb[3 * cidx + 1];
    float cz = xb[3 * cidx + 2];

    // ---- ball query ----
    int cnt = 0;
    for (int bs = 0; bs < NPTS; bs += 64) {
        int i = bs + s;
        float dx = __fsub_rn(xb[3 * i + 0], cx);
        float dy = __fsub_rn(xb[3 * i + 1], cy);
        float dz = __fsub_rn(xb[3 * i + 2], cz);
        float d2 = __fadd_rn(__fadd_rn(__fmul_rn(dx, dx), __fmul_rn(dy, dy)), __fmul_rn(dz, dz));
        bool inb = d2 < R2;
        unsigned long long m = __ballot(inb);
        int pre = (int)__popcll(m & ((1ull << s) - 1ull));
        int slot = cnt + pre;
        if (inb && slot < NSAMPLE) slots[slot] = i;
        cnt += (int)__popcll(m);
        if (cnt >= NSAMPLE) break;
    }
    __syncthreads();
    int first = (cnt > 0) ? slots[0] : 0;
    int i = (s < cnt) ? slots[s] : first;

    // ---- gather into X (column-major [c][lane]) ----
    const float* pp = xyz + ((size_t)b * NPTS + i) * 3;
    X[64][s] = pp[0] - cx;
    X[65][s] = pp[1] - cy;
    X[66][s] = pp[2] - cz;
    const float4* fr = (const float4*)(feats_t + ((size_t)b * NPTS + i) * CIN);
    #pragma unroll
    for (int q = 0; q < 16; ++q) {
        float4 f = fr[q];
        X[q * 4 + 0][s] = f.x;
        X[q * 4 + 1][s] = f.y;
        X[q * 4 + 2][s] = f.z;
        X[q * 4 + 3][s] = f.w;
    }

    // ---- layer 1: 67 -> 64.  x order = [feats(64), dxyz(3)] so W1 row = (c<64 ? c+3 : c-64)
    float acc[64];
    #pragma unroll
    for (int o = 0; o < 64; ++o) acc[o] = b1[o];
    for (int c = 0; c < 67; ++c) {
        float xc = X[c][s];
        const float* w = W1 + ((c < 64) ? (c + 3) : (c - 64)) * 64;
        #pragma unroll
        for (int o = 0; o < 64; ++o) acc[o] = fmaf(xc, w[o], acc[o]);
    }
    #pragma unroll
    for (int o = 0; o < 64; ++o) X[o][s] = fmaxf(acc[o], 0.0f);

    // ---- layer 2: 64 -> 64 ----
    #pragma unroll
    for (int o = 0; o < 64; ++o) acc[o] = b2[o];
    for (int c = 0; c < 64; ++c) {
        float xc = X[c][s];
        const float* w = W2 + c * 64;
        #pragma unroll
        for (int o = 0; o < 64; ++o) acc[o] = fmaf(xc, w[o], acc[o]);
    }
    #pragma unroll
    for (int o = 0; o < 64; ++o) X[o][s] = fmaxf(acc[o], 0.0f);

    // ---- layer 3: 64 -> 128 ----
    float h3[128];
    #pragma unroll
    for (int o = 0; o < 128; ++o) h3[o] = b3[o];
    for (int c = 0; c < 64; ++c) {
        float xc = X[c][s];
        const float* w = W3 + c * 128;
        #pragma unroll
        for (int o = 0; o < 128; ++o) h3[o] = fmaf(xc, w[o], h3[o]);
    }

    // ---- relu + maxpool over the 64 samples via DPP (true max lands in lane 63) ----
    #pragma unroll
    for (int o = 0; o < 128; ++o)
        h3[o] = wave_max_f(fmaxf(h3[o], 0.0f));
    if (s == 63) {
        float* op = out + (size_t)cent * 128;
        #pragma unroll
        for (int o = 0; o < 128; o += 4) {
            float4 v = make_float4(h3[o], h3[o + 1], h3[o + 2], h3[o + 3]);
            *(float4*)&op[o] = v;
        }
    }
}

extern "C" void kernel_launch(void* const* d_in, const int* in_sizes, int n_in,
                              void* d_out, int out_size, void* d_ws, size_t ws_size,
                              hipStream_t stream) {
    const float* xyz   = (const float*)d_in[0];
    const float* feats = (const float*)d_in[1];
    const float* W1 = (const float*)d_in[2];
    const float* b1 = (const float*)d_in[3];
    const float* W2 = (const float*)d_in[4];
    const float* b2 = (const float*)d_in[5];
    const float* W3 = (const float*)d_in[6];
    const float* b3 = (const float*)d_in[7];
    float* out = (float*)d_out;

    char* ws = (char*)d_ws;
    int*   fps_idx = (int*)ws;                     // 16 KB
    u64*   slots   = (u64*)(ws + 16384);           // 8 batches x 2 parity x 4 parts x 8 B
    float* feats_t = (float*)(ws + 65536);         // 32 MB

    transpose_kernel<<<NB * (NPTS / 64), 256, 0, stream>>>(feats, feats_t);
    fps_kernel<<<NB * PARTS, 512, 0, stream>>>(xyz, fps_idx, slots);
    ballmlp_kernel<<<NB * NPOINT, 64, 0, stream>>>(xyz, feats_t, fps_idx,
                                                   W1, b1, W2, b2, W3, b3, out);
}

// Round 15
// 1295.358 us; speedup vs baseline: 3.5343x; 3.5343x over previous
//
#include <hip/hip_runtime.h>

#define NB 8
#define NPTS 16384
#define NPOINT 512
#define NSAMPLE 64
#define CIN 64

typedef float v2f __attribute__((ext_vector_type(2)));

template <int CTRL>
__device__ __forceinline__ float dpp_f(float x) {
    int xi = __builtin_bit_cast(int, x);
    int yi = __builtin_amdgcn_update_dpp(xi, xi, CTRL, 0xF, 0xF, false);
    return __builtin_bit_cast(float, yi);
}
template <int CTRL>
__device__ __forceinline__ int dpp_i(int x) {
    return __builtin_amdgcn_update_dpp(x, x, CTRL, 0xF, 0xF, false);
}

// wave64 max reduce -> true result in lane 63
__device__ __forceinline__ float wave_max_f(float x) {
    x = fmaxf(x, dpp_f<0x111>(x));   // row_shr:1
    x = fmaxf(x, dpp_f<0x112>(x));   // row_shr:2
    x = fmaxf(x, dpp_f<0x114>(x));   // row_shr:4
    x = fmaxf(x, dpp_f<0x118>(x));   // row_shr:8
    x = fmaxf(x, dpp_f<0x142>(x));   // row_bcast:15
    x = fmaxf(x, dpp_f<0x143>(x));   // row_bcast:31
    return x;
}
__device__ __forceinline__ int wave_min_i(int x) {
    x = min(x, dpp_i<0x111>(x));
    x = min(x, dpp_i<0x112>(x));
    x = min(x, dpp_i<0x114>(x));
    x = min(x, dpp_i<0x118>(x));
    x = min(x, dpp_i<0x142>(x));
    x = min(x, dpp_i<0x143>(x));
    return x;
}

// ---------------- prep: feature transpose (blocks 0..2047) + xyz AoS->SoA (2048..2055) ----
__global__ __launch_bounds__(256) void prep_kernel(
    const float* __restrict__ feats, const float* __restrict__ xyz,
    float* __restrict__ feats_t,
    float* __restrict__ xs, float* __restrict__ ys, float* __restrict__ zs)
{
    int blk = blockIdx.x;
    int tid = threadIdx.x;
    if (blk >= 2048) {
        // xyz (B,N,3) -> xs/ys/zs SoA
        int b = blk - 2048;
        const float* xb = xyz + (size_t)b * NPTS * 3;
        float* xsb = xs + (size_t)b * NPTS;
        float* ysb = ys + (size_t)b * NPTS;
        float* zsb = zs + (size_t)b * NPTS;
        for (int k = 0; k < NPTS / 256; ++k) {
            int i = k * 256 + tid;
            xsb[i] = xb[3 * i + 0];
            ysb[i] = xb[3 * i + 1];
            zsb[i] = xb[3 * i + 2];
        }
        return;
    }
    __shared__ float t[64][65];
    int b = blk & 7, tile = blk >> 3, n0 = tile * 64;
    int cc = tid & 63, rr = tid >> 6;           // rr 0..3
    const float* fb = feats + (size_t)b * CIN * NPTS;
    #pragma unroll
    for (int k = 0; k < 16; ++k) {
        int c = k * 4 + rr;
        t[c][cc] = fb[(size_t)c * NPTS + n0 + cc];
    }
    __syncthreads();
    float* fo = feats_t + ((size_t)b * NPTS + n0) * CIN;
    #pragma unroll
    for (int k = 0; k < 16; ++k) {
        int n = k * 4 + rr;
        fo[(size_t)n * CIN + cc] = t[cc][n];
    }
}

// ---------------- FPS: one block per batch; x,y in LDS, z+dd in registers ----------------
__global__ __launch_bounds__(512) __attribute__((amdgpu_waves_per_eu(2, 2)))
void fps_kernel(
    const float* __restrict__ xs, const float* __restrict__ ys,
    const float* __restrict__ zs, int* __restrict__ fps_idx)
{
    // chunk-major: [chunk g][tid][elem] -> lane stride 16 B -> conflict-free ds_read_b128
    __shared__ float x_lds[8][512][4];            // 64 KB
    __shared__ float y_lds[8][512][4];            // 64 KB
    __shared__ __align__(16) int s_pub[2][8][8];  // (val,idx,x,y,z) per wave, parity-buffered

    const int b = blockIdx.x;
    const int tid = threadIdx.x;
    const int wv = tid >> 6, ln = tid & 63;
    const float* xsb = xs + (size_t)b * NPTS;
    const float* ysb = ys + (size_t)b * NPTS;
    const float* zsb = zs + (size_t)b * NPTS;

    // init: stage x,y into LDS; z (32 floats) + dd (32) live in registers
    v2f z2[16], dd2[16];
    {
        const float4* XS4 = (const float4*)xsb;
        const float4* YS4 = (const float4*)ysb;
        const float4* ZS4 = (const float4*)zsb;
        #pragma unroll
        for (int g = 0; g < 8; ++g) {
            float4 fx = XS4[tid * 8 + g];
            float4 fy = YS4[tid * 8 + g];
            float4 fz = ZS4[tid * 8 + g];
            *(float4*)&x_lds[g][tid][0] = fx;
            *(float4*)&y_lds[g][tid][0] = fy;
            z2[2 * g + 0] = (v2f){fz.x, fz.y};
            z2[2 * g + 1] = (v2f){fz.z, fz.w};
        }
        #pragma unroll
        for (int m = 0; m < 16; ++m) dd2[m] = (v2f){1e10f, 1e10f};
    }
    if (tid == 0) fps_idx[b * NPOINT] = 0;
    float cx = xsb[0], cy = ysb[0], cz = zsb[0];   // centroid 0 = point 0
    __syncthreads();

    for (int j = 1; j < NPOINT; ++j) {
        #pragma clang fp contract(off)
        const int p = j & 1;
        v2f ncx = (v2f){-cx, -cx};
        v2f ncy = (v2f){-cy, -cy};
        v2f ncz = (v2f){-cz, -cz};
        // ---- distance update: x,y from LDS, z/dd in regs (exact numpy rounding) ----
        float bm = -1.0f;
        #pragma unroll
        for (int g = 0; g < 8; ++g) {
            float4 fx = *(const float4*)&x_lds[g][tid][0];
            float4 fy = *(const float4*)&y_lds[g][tid][0];
            // pair lo: points 4g+0, 4g+1
            v2f dxl = (v2f){fx.x, fx.y} + ncx;     // a + (-c) == a - c exactly
            v2f dyl = (v2f){fy.x, fy.y} + ncy;
            v2f dzl = z2[2 * g + 0] + ncz;
            v2f d2l = (dxl * dxl + dyl * dyl) + dzl * dzl;   // (x²+y²)+z², each rounded
            v2f ndl = __builtin_elementwise_min(dd2[2 * g + 0], d2l);
            dd2[2 * g + 0] = ndl;
            // pair hi: points 4g+2, 4g+3
            v2f dxh = (v2f){fx.z, fx.w} + ncx;
            v2f dyh = (v2f){fy.z, fy.w} + ncy;
            v2f dzh = z2[2 * g + 1] + ncz;
            v2f d2h = (dxh * dxh + dyh * dyh) + dzh * dzh;
            v2f ndh = __builtin_elementwise_min(dd2[2 * g + 1], d2h);
            dd2[2 * g + 1] = ndh;
            bm = fmaxf(bm, fmaxf(fmaxf(ndl.x, ndl.y), fmaxf(ndh.x, ndh.y)));
        }
        // ---- wave max via DPP ----
        float wm = wave_max_f(bm);
        float wmax = __builtin_bit_cast(float,
            __builtin_amdgcn_readlane(__builtin_bit_cast(int, wm), 63));
        // ---- masked scan: first matching sub-index (descending chain -> smallest) ----
        int mk = 32;
        if (bm == wmax) {
            #pragma unroll
            for (int m = 15; m >= 0; --m) {
                mk = (dd2[m].y == wmax) ? (2 * m + 1) : mk;
                mk = (dd2[m].x == wmax) ? (2 * m)     : mk;
            }
        }
        int mi = (mk == 32) ? 0x7fffffff : (tid * 32 + mk);
        // ---- wave min-index via DPP ----
        int rm = wave_min_i(mi);
        int wmi = __builtin_amdgcn_readlane(rm, 63);
        // ---- unique publisher lane writes (val, idx, x, y, z) ----
        if (mi == wmi && mk != 32) {
            int g = mk >> 2, e = mk & 3;
            float cpx = x_lds[g][tid][e];          // dynamic-e LDS read (not regs)
            float cpy = y_lds[g][tid][e];
            float cpz = zsb[mi];                   // masked global load, pre-barrier
            s_pub[p][wv][0] = __builtin_bit_cast(int, wmax);
            s_pub[p][wv][1] = mi;
            s_pub[p][wv][2] = __builtin_bit_cast(int, cpx);
            s_pub[p][wv][3] = __builtin_bit_cast(int, cpy);
            s_pub[p][wv][4] = __builtin_bit_cast(int, cpz);
        }
        __syncthreads();                           // single barrier per iteration
        // ---- cross-wave argmax over 8 slots, carrying coords (3-stage DPP) ----
        int4 q = *(const int4*)&s_pub[p][ln & 7][0];
        int qz = s_pub[p][ln & 7][4];
        float v = __builtin_bit_cast(float, q.x);
        int ii = q.y, xc = q.z, yc = q.w, zc = qz;
        {
            float ov; int oi, ox, oy, oz; bool tk;
            ov = dpp_f<0x111>(v); oi = dpp_i<0x111>(ii);
            ox = dpp_i<0x111>(xc); oy = dpp_i<0x111>(yc); oz = dpp_i<0x111>(zc);
            tk = (ov > v) || (ov == v && oi < ii);
            v = tk ? ov : v; ii = tk ? oi : ii; xc = tk ? ox : xc; yc = tk ? oy : yc; zc = tk ? oz : zc;
            ov = dpp_f<0x112>(v); oi = dpp_i<0x112>(ii);
            ox = dpp_i<0x112>(xc); oy = dpp_i<0x112>(yc); oz = dpp_i<0x112>(zc);
            tk = (ov > v) || (ov == v && oi < ii);
            v = tk ? ov : v; ii = tk ? oi : ii; xc = tk ? ox : xc; yc = tk ? oy : yc; zc = tk ? oz : zc;
            ov = dpp_f<0x114>(v); oi = dpp_i<0x114>(ii);
            ox = dpp_i<0x114>(xc); oy = dpp_i<0x114>(yc); oz = dpp_i<0x114>(zc);
            tk = (ov > v) || (ov == v && oi < ii);
            v = tk ? ov : v; ii = tk ? oi : ii; xc = tk ? ox : xc; yc = tk ? oy : yc; zc = tk ? oz : zc;
        }
        int ch = __builtin_amdgcn_readlane(ii, 7);
        cx = __builtin_bit_cast(float, __builtin_amdgcn_readlane(xc, 7));
        cy = __builtin_bit_cast(float, __builtin_amdgcn_readlane(yc, 7));
        cz = __builtin_bit_cast(float, __builtin_amdgcn_readlane(zc, 7));
        if (tid == 0) fps_idx[b * NPOINT + j] = ch;
    }
}

// ---------------- fused ball query + gather + MLP(67->64->64->128) + maxpool ----------------
// one wave per centroid; SoA coalesced ball scan
__global__ __launch_bounds__(64) void ballmlp_kernel(
    const float* __restrict__ xyz,
    const float* __restrict__ xs, const float* __restrict__ ys, const float* __restrict__ zs,
    const float* __restrict__ feats_t, const int* __restrict__ fps_idx,
    const float* __restrict__ W1, const float* __restrict__ b1,
    const float* __restrict__ W2, const float* __restrict__ b2,
    const float* __restrict__ W3, const float* __restrict__ b3,
    float* __restrict__ out)
{
    const float R2 = (float)(0.1 * 0.1);   // double product rounded to f32 (matches numpy)
    int blk = blockIdx.x;
    int b = blk & 7, j = blk >> 3;
    int s = threadIdx.x;
    int cent = b * NPOINT + j;
    const float* xsb = xs + (size_t)b * NPTS;
    const float* ysb = ys + (size_t)b * NPTS;
    const float* zsb = zs + (size_t)b * NPTS;

    __shared__ float X[67][64];   // column-major: X[c][s] -> lane-contiguous, conflict-free
    __shared__ int slots[64];

    int cidx = fps_idx[cent];
    float cx = xsb[cidx];
    float cy = ysb[cidx];
    float cz = zsb[cidx];

    // ---- ball query (SoA coalesced) ----
    int cnt = 0;
    for (int bs = 0; bs < NPTS; bs += 64) {
        int i = bs + s;
        float dx = __fsub_rn(xsb[i], cx);
        float dy = __fsub_rn(ysb[i], cy);
        float dz = __fsub_rn(zsb[i], cz);
        float d2 = __fadd_rn(__fadd_rn(__fmul_rn(dx, dx), __fmul_rn(dy, dy)), __fmul_rn(dz, dz));
        bool inb = d2 < R2;
        unsigned long long m = __ballot(inb);
        int pre = (int)__popcll(m & ((1ull << s) - 1ull));
        int slot = cnt + pre;
        if (inb && slot < NSAMPLE) slots[slot] = i;
        cnt += (int)__popcll(m);
        if (cnt >= NSAMPLE) break;
    }
    __syncthreads();
    int first = (cnt > 0) ? slots[0] : 0;
    int i = (s < cnt) ? slots[s] : first;

    // ---- gather into X (column-major [c][lane]); dxyz via AoS (one cache line) ----
    const float* pp = xyz + ((size_t)b * NPTS + i) * 3;
    X[64][s] = pp[0] - cx;
    X[65][s] = pp[1] - cy;
    X[66][s] = pp[2] - cz;
    const float4* fr = (const float4*)(feats_t + ((size_t)b * NPTS + i) * CIN);
    #pragma unroll
    for (int q = 0; q < 16; ++q) {
        float4 f = fr[q];
        X[q * 4 + 0][s] = f.x;
        X[q * 4 + 1][s] = f.y;
        X[q * 4 + 2][s] = f.z;
        X[q * 4 + 3][s] = f.w;
    }

    // ---- layer 1: 67 -> 64.  x order = [feats(64), dxyz(3)] so W1 row = (c<64 ? c+3 : c-64)
    float acc[64];
    #pragma unroll
    for (int o = 0; o < 64; ++o) acc[o] = b1[o];
    for (int c = 0; c < 67; ++c) {
        float xc = X[c][s];
        const float* w = W1 + ((c < 64) ? (c + 3) : (c - 64)) * 64;
        #pragma unroll
        for (int o = 0; o < 64; ++o) acc[o] = fmaf(xc, w[o], acc[o]);
    }
    #pragma unroll
    for (int o = 0; o < 64; ++o) X[o][s] = fmaxf(acc[o], 0.0f);

    // ---- layer 2: 64 -> 64 ----
    #pragma unroll
    for (int o = 0; o < 64; ++o) acc[o] = b2[o];
    for (int c = 0; c < 64; ++c) {
        float xc = X[c][s];
        const float* w = W2 + c * 64;
        #pragma unroll
        for (int o = 0; o < 64; ++o) acc[o] = fmaf(xc, w[o], acc[o]);
    }
    #pragma unroll
    for (int o = 0; o < 64; ++o) X[o][s] = fmaxf(acc[o], 0.0f);

    // ---- layer 3: 64 -> 128 ----
    float h3[128];
    #pragma unroll
    for (int o = 0; o < 128; ++o) h3[o] = b3[o];
    for (int c = 0; c < 64; ++c) {
        float xc = X[c][s];
        const float* w = W3 + c * 128;
        #pragma unroll
        for (int o = 0; o < 128; ++o) h3[o] = fmaf(xc, w[o], h3[o]);
    }

    // ---- relu + maxpool over 64 lanes via DPP (true max lands in lane 63) ----
    #pragma unroll
    for (int o = 0; o < 128; ++o)
        h3[o] = wave_max_f(fmaxf(h3[o], 0.0f));
    if (s == 63) {
        float* op = out + (size_t)cent * 128;
        #pragma unroll
        for (int o = 0; o < 128; o += 4) {
            float4 v = make_float4(h3[o], h3[o + 1], h3[o + 2], h3[o + 3]);
            *(float4*)&op[o] = v;
        }
    }
}

extern "C" void kernel_launch(void* const* d_in, const int* in_sizes, int n_in,
                              void* d_out, int out_size, void* d_ws, size_t ws_size,
                              hipStream_t stream) {
    const float* xyz   = (const float*)d_in[0];
    const float* feats = (const float*)d_in[1];
    const float* W1 = (const float*)d_in[2];
    const float* b1 = (const float*)d_in[3];
    const float* W2 = (const float*)d_in[4];
    const float* b2 = (const float*)d_in[5];
    const float* W3 = (const float*)d_in[6];
    const float* b3 = (const float*)d_in[7];
    float* out = (float*)d_out;

    // layout proven ≤ ws_size by R7 (35.7 MB)
    char* ws = (char*)d_ws;
    int*   fps_idx = (int*)ws;                          // 16 KB
    float* xs = (float*)(ws + 16384);                   // 512 KB
    float* ys = (float*)(ws + 16384 + 524288);          // 512 KB
    float* zs = (float*)(ws + 16384 + 2 * 524288);      // 512 KB
    float* feats_t = (float*)(ws + 16384 + 4 * 524288); // 32 MB

    prep_kernel<<<2048 + NB, 256, 0, stream>>>(feats, xyz, feats_t, xs, ys, zs);
    fps_kernel<<<NB, 512, 0, stream>>>(xs, ys, zs, fps_idx);
    ballmlp_kernel<<<NB * NPOINT, 64, 0, stream>>>(xyz, xs, ys, zs, feats_t, fps_idx,
                                                   W1, b1, W2, b2, W3, b3, out);
}